// Round 9
// baseline (133.618 us; speedup 1.0000x reference)
//
#include <hip/hip_runtime.h>

#define TB 256
#define NA_G (32 * 12 * 1024)   // 16B-groups in A tiles
#define NB_G (64 * 12 * 1024)   // 16B-groups in B tiles
#define NEED_T ((size_t)(NA_G + NB_G) * 16)          // 18.87 MB bf16 tiles
#define NEED_S ((size_t)8192 * 4096 * 2)             // 67.1 MB bf16 S

typedef __bf16 bf16x8 __attribute__((ext_vector_type(8)));
typedef float f32x4 __attribute__((ext_vector_type(4)));
typedef unsigned u32x4 __attribute__((ext_vector_type(4)));
typedef unsigned u32x2 __attribute__((ext_vector_type(2)));
typedef unsigned long long ull;

__device__ __forceinline__ unsigned pack2bf(float a, float b) {
  unsigned ua = __float_as_uint(a), ub = __float_as_uint(b);
  ua = (ua + 0x7fffu + ((ua >> 16) & 1u)) >> 16;   // RNE f32->bf16
  ub = (ub + 0x7fffu + ((ub >> 16) & 1u)) >> 16;
  return ua | (ub << 16);
}
__device__ __forceinline__ unsigned akey16(unsigned bits) {
  return (bits & 0x8000u) ? (bits ^ 0xFFFFu) : (bits | 0x8000u);
}
__device__ __forceinline__ float akey2f(unsigned ak) {
  unsigned bits = (ak & 0x8000u) ? (ak ^ 0x8000u) : (ak ^ 0xFFFFu);
  return __uint_as_float(bits << 16);
}
__device__ __forceinline__ float bf2f(unsigned bits) {
  return __uint_as_float(bits << 16);
}
__device__ __forceinline__ void gll16(const void* g, void* l) {
  __builtin_amdgcn_global_load_lds(
      (const __attribute__((address_space(1))) unsigned*)g,
      (__attribute__((address_space(3))) unsigned*)l, 16, 0, 0);
}

// Pre-convert f32 -> bf16 into XOR-swizzled 128x64 tiles (LDS-image layout)
__global__ __launch_bounds__(256) void convert_pack(
    const float* __restrict__ q, const float* __restrict__ p,
    unsigned char* __restrict__ qt, unsigned char* __restrict__ pt) {
  int g = blockIdx.x * 256 + threadIdx.x;
  const float* src;
  unsigned char* dst;
  if (g < NA_G) { src = q; dst = qt; }
  else { g -= NA_G; src = p; dst = pt; }
  int tile = g >> 10;
  int o = (g & 1023) * 16;
  int row = o >> 7;
  int colb = (o & 127) ^ ((row & 7) << 4);
  int rb = tile / 12, kt = tile - rb * 12;
  const float* s = src + ((size_t)(rb * 128 + row)) * 768 + kt * 64 + (colb >> 1);
  float4 a = ((const float4*)s)[0];
  float4 b = ((const float4*)s)[1];
  uint4 w;
  w.x = pack2bf(a.x, a.y); w.y = pack2bf(a.z, a.w);
  w.z = pack2bf(b.x, b.y); w.w = pack2bf(b.z, b.w);
  *(uint4*)(dst + (size_t)tile * 16384 + o) = w;
}

// ========== kernel 1: LDS-staged GEMM -> S (bf16, coalesced NT stores) ==========
template <int PATH>
__global__ __launch_bounds__(TB, 4) void dpr_gemm(
    const float* __restrict__ q_emb, const float* __restrict__ p_emb,
    const unsigned char* __restrict__ qt, const unsigned char* __restrict__ pt,
    unsigned short* __restrict__ Sout) {
  __shared__ __align__(16) char arena[32768];
  unsigned short* Al = (unsigned short*)arena;
  unsigned short* Bl = (unsigned short*)(arena + 16384);

  const int tid = threadIdx.x, lane = tid & 63, wid = tid >> 6;
  int g = blockIdx.x;
  int rg = g & 7, w = g >> 3;
  int blockB = (rg >> 2) * 16 + (w & 15);
  int blockP = (rg & 3) * 16 + (w >> 4);
  const int lr = lane & 15, lg = lane >> 4;
  const int db = wid >> 1, dp = wid & 1;

  f32x4 acc[4][4];
  #pragma unroll
  for (int m = 0; m < 4; ++m)
    #pragma unroll
    for (int n = 0; n < 4; ++n)
      acc[m][n] = f32x4{0.f, 0.f, 0.f, 0.f};

  const float* Abase = q_emb + (size_t)(blockB * 128) * 768;
  const float* Bbase = p_emb + (size_t)(blockP * 128) * 768;

  for (int kt = 0; kt < 12; ++kt) {
    if (PATH == 1) {
      const unsigned char* qtile = qt + ((size_t)(blockB * 12 + kt)) * 16384;
      const unsigned char* ptile = pt + ((size_t)(blockP * 12 + kt)) * 16384;
      #pragma unroll
      for (int c2 = 0; c2 < 4; ++c2) {
        int chunk = wid * 4 + c2;
        gll16(qtile + chunk * 1024 + lane * 16, (char*)Al + chunk * 1024);
        gll16(ptile + chunk * 1024 + lane * 16, (char*)Bl + chunk * 1024);
      }
    } else {
      const int k0 = kt * 64;
      #pragma unroll
      for (int it = 0; it < 4; ++it) {
        int gg = tid + 256 * it;
        int row = gg >> 3;
        int col = (gg & 7) * 8;
        int off = (row * 128 + col * 2) ^ ((row & 7) << 4);
        const float4* sA = (const float4*)(Abase + (size_t)row * 768 + k0 + col);
        float4 a0 = sA[0], a1 = sA[1];
        uint4 wv;
        wv.x = pack2bf(a0.x, a0.y); wv.y = pack2bf(a0.z, a0.w);
        wv.z = pack2bf(a1.x, a1.y); wv.w = pack2bf(a1.z, a1.w);
        *(uint4*)((char*)Al + off) = wv;
        const float4* sB = (const float4*)(Bbase + (size_t)row * 768 + k0 + col);
        float4 b0 = sB[0], b1 = sB[1];
        wv.x = pack2bf(b0.x, b0.y); wv.y = pack2bf(b0.z, b0.w);
        wv.z = pack2bf(b1.x, b1.y); wv.w = pack2bf(b1.z, b1.w);
        *(uint4*)((char*)Bl + off) = wv;
      }
    }
    __syncthreads();
    #pragma unroll
    for (int ks = 0; ks < 2; ++ks) {
      bf16x8 af[4], bfr[4];
      #pragma unroll
      for (int m = 0; m < 4; ++m) {
        int row = db * 64 + m * 16 + lr;
        int off = (row * 128 + ks * 64 + lg * 16) ^ ((row & 7) << 4);
        af[m] = *(const bf16x8*)((const char*)Al + off);
      }
      #pragma unroll
      for (int n = 0; n < 4; ++n) {
        int row = dp * 64 + n * 16 + lr;
        int off = (row * 128 + ks * 64 + lg * 16) ^ ((row & 7) << 4);
        bfr[n] = *(const bf16x8*)((const char*)Bl + off);
      }
      #pragma unroll
      for (int m = 0; m < 4; ++m)
        #pragma unroll
        for (int n = 0; n < 4; ++n)
          acc[m][n] = __builtin_amdgcn_mfma_f32_16x16x32_bf16(af[m], bfr[n], acc[m][n], 0, 0, 0);
    }
    __syncthreads();
  }

  // epilogue: stage S quadrant in LDS (XOR-swizzled), stream out coalesced NT
  char* Sq = arena + wid * 8192;
  #pragma unroll
  for (int m = 0; m < 4; ++m)
    #pragma unroll
    for (int n = 0; n < 4; ++n) {
      int row = n * 16 + lr;
      int byte = row * 128 + m * 32 + lg * 8;
      int swz = byte ^ ((row & 7) << 4);
      u32x2 wv;
      wv.x = pack2bf(acc[m][n][0], acc[m][n][1]);
      wv.y = pack2bf(acc[m][n][2], acc[m][n][3]);
      *(u32x2*)(Sq + swz) = wv;
    }
  const int pair = (blockB * 2 + db) * 128 + blockP * 2 + dp;
  unsigned short* Sp = Sout + ((size_t)pair << 12);
  #pragma unroll
  for (int i = 0; i < 8; ++i) {
    int base = i * 1024 + lane * 16;
    int swz = base ^ ((lane >> 3) << 4);
    u32x4 v = *(const u32x4*)(Sq + swz);
    __builtin_nontemporal_store(v, (u32x4*)((char*)Sp + base));
  }
}

// count-only rank scan over a 256-bin hist
__device__ __forceinline__ void scanC(const unsigned* h, int lane, int R,
                                      bool top, int& selB, int& Rin, int& cnt) {
  uint4 h4 = ((const uint4*)h)[lane];
  unsigned lsum = h4.x + h4.y + h4.z + h4.w;
  unsigned run = lsum;
  if (top) {
    #pragma unroll
    for (int off = 1; off < 64; off <<= 1) {
      unsigned o = __shfl_down(run, off);
      if (lane + off < 64) run += o;
    }
  } else {
    #pragma unroll
    for (int off = 1; off < 64; off <<= 1) {
      unsigned o = __shfl_up(run, off);
      if (lane >= off) run += o;
    }
  }
  unsigned excl = run - lsum;
  bool found = ((unsigned)R > excl) && ((unsigned)R <= run);
  int sb = 0, ri = 0, cc = 0;
  if (found) {
    unsigned a = excl;
    if (top) {
      if ((unsigned)R <= a + h4.w) { sb = 3; ri = R - (int)a; cc = (int)h4.w; }
      else { a += h4.w;
      if ((unsigned)R <= a + h4.z) { sb = 2; ri = R - (int)a; cc = (int)h4.z; }
      else { a += h4.z;
      if ((unsigned)R <= a + h4.y) { sb = 1; ri = R - (int)a; cc = (int)h4.y; }
      else { a += h4.y; sb = 0; ri = R - (int)a; cc = (int)h4.x; } } }
    } else {
      if ((unsigned)R <= a + h4.x) { sb = 0; ri = R - (int)a; cc = (int)h4.x; }
      else { a += h4.x;
      if ((unsigned)R <= a + h4.y) { sb = 1; ri = R - (int)a; cc = (int)h4.y; }
      else { a += h4.y;
      if ((unsigned)R <= a + h4.z) { sb = 2; ri = R - (int)a; cc = (int)h4.z; }
      else { a += h4.z; sb = 3; ri = R - (int)a; cc = (int)h4.w; } } }
    }
    sb += lane * 4;
  }
  ull fm = __ballot(found);
  int src = fm ? (int)__builtin_ctzll(fm) : 0;
  selB = __shfl(sb, src); Rin = __shfl(ri, src); cnt = __shfl(cc, src);
}

// ==== kernel 2: register-cached selection, linear bins + ballot radix-select ====
#define FOREACH_VALID(BODY)                                   \
  _Pragma("unroll") for (int t = 0; t < 8; ++t) {             \
    if ((pm8 >> t) & 1u) {                                    \
      _Pragma("unroll") for (int jj = 0; jj < 8; ++jj) {      \
        if ((qm8 >> jj) & 1u) {                               \
          unsigned u = vv[t][jj >> 1];                        \
          unsigned bits = (jj & 1) ? (u >> 16) : (u & 0xFFFFu); \
          const int eidx = t * 8 + jj;                        \
          BODY                                                \
        } } } }

__global__ __launch_bounds__(TB, 6) void dpr_select(
    const unsigned short* __restrict__ S,
    const void* __restrict__ qmr, const void* __restrict__ pmr,
    const float* __restrict__ alpha_raw, const float* __restrict__ beta_raw,
    float* __restrict__ out) {
  __shared__ unsigned harena[4][336];   // per wave: hist[256] | list[64] | lcnt
  const int tid = threadIdx.x, lane = tid & 63, wid = tid >> 6;
  const int pair = blockIdx.x * 4 + wid;
  const int b = pair >> 7, p = pair & 127;

  bool m32 = true;
  {
    const unsigned* qm32 = (const unsigned*)qmr;
    #pragma unroll
    for (int i = 0; i < 8; ++i) m32 = m32 && (qm32[i] <= 1u);
  }
  bool qvb = m32 ? (((const int*)qmr)[b * 64 + lane] != 0)
                 : (((const unsigned char*)qmr)[b * 64 + lane] != 0);
  bool pvb = m32 ? (((const int*)pmr)[p * 64 + lane] != 0)
                 : (((const unsigned char*)pmr)[p * 64 + lane] != 0);
  ull qb = __ballot(qvb);
  ull pb = __ballot(pvb);
  const int n_pair = __popcll(qb) * __popcll(pb);
  if (n_pair == 0) {
    if (lane == 0) out[pair] = -1e9f;
    return;
  }

  int ksel = 4 * n_pair / 10; if (ksel < 1) ksel = 1;
  int lsel = 2 * n_pair / 10; if (lsel < 1) lsel = 1;

  // load this pair's 64 values / lane ONCE into registers
  const unsigned short* Sp = S + ((size_t)pair << 12);
  u32x4 vv[8];
  #pragma unroll
  for (int t = 0; t < 8; ++t)
    vv[t] = __builtin_nontemporal_load((const u32x4*)(Sp + t * 512 + lane * 8));

  const unsigned qm8 = (unsigned)((qb >> ((lane & 7) * 8)) & 0xFFull);
  unsigned pm8 = 0;
  #pragma unroll
  for (int t = 0; t < 8; ++t)
    pm8 |= (unsigned)((pb >> (t * 8 + (lane >> 3))) & 1ull) << t;

  unsigned* hist = harena[wid];
  unsigned* list = harena[wid] + 256;
  unsigned* lcnt = harena[wid] + 320;

  // pass A: tsum + integer min/max on monotone keys (shfl only)
  float tsum = 0.f;
  unsigned akmn = 0xFFFFu, akmx = 0u;
  FOREACH_VALID({
    (void)eidx;
    unsigned ak = akey16(bits);
    akmn = akmn < ak ? akmn : ak;
    akmx = akmx > ak ? akmx : ak;
    tsum += bf2f(bits);
  })
  #pragma unroll
  for (int off = 1; off < 64; off <<= 1) {
    tsum += __shfl_xor(tsum, off);
    unsigned on = __shfl_xor(akmn, off); akmn = akmn < on ? akmn : on;
    unsigned ox = __shfl_xor(akmx, off); akmx = akmx > ox ? akmx : ox;
  }

  unsigned akT, akB;
  if (akmx == akmn) {
    akT = akmn; akB = akmn;   // all valid values identical
  } else {
    const float mnf = akey2f(akmn), mxf = akey2f(akmx);
    const float sc0 = 255.0f / (mxf - mnf);

    // pass B: linear count histogram, bins packed into 16 VGPRs
    ((uint4*)hist)[lane] = uint4{0u, 0u, 0u, 0u};
    unsigned bpk[16];
    #pragma unroll
    for (int i = 0; i < 16; ++i) bpk[i] = 0u;
    FOREACH_VALID({
      int bn = (int)((bf2f(bits) - mnf) * sc0);
      bn = bn < 0 ? 0 : (bn > 255 ? 255 : bn);
      bpk[eidx >> 2] |= (unsigned)bn << ((eidx & 3) * 8);
      atomicAdd(&hist[bn], 1u);
    })

    int sbT, RT, cT, sbB, RB, cB;
    scanC(hist, lane, ksel, true, sbT, RT, cT);
    scanC(hist, lane, lsel, false, sbB, RB, cB);

    // gather rank-bin candidates -> ballot radix-select exact bf16 key
    auto gatherSel = [&](bool largest, int sb0, int R, int c) -> unsigned {
      int sub0 = -1;   // -1: no sub-refine
      if (c > 64) {    // linear sub-refine within the bin (rare)
        ((uint4*)hist)[lane] = uint4{0u, 0u, 0u, 0u};
        const float w0 = (mxf - mnf) * (1.0f / 255.0f);
        const float lo = mnf + w0 * (float)sb0;
        const float sc1 = 255.0f / w0;
        FOREACH_VALID({
          int bn = (int)((bpk[eidx >> 2] >> ((eidx & 3) * 8)) & 255u);
          if (bn == sb0) {
            int sb2 = (int)((bf2f(bits) - lo) * sc1);
            sb2 = sb2 < 0 ? 0 : (sb2 > 255 ? 255 : sb2);
            atomicAdd(&hist[sb2], 1u);
          }
        })
        int s2, r2, c2;
        scanC(hist, lane, R, largest, s2, r2, c2);
        sub0 = s2; R = r2; c = c2;
      }
      if (lane == 0) *lcnt = 0u;
      const float w0 = (mxf - mnf) * (1.0f / 255.0f);
      const float lo = mnf + w0 * (float)sb0;
      const float sc1 = 255.0f / w0;
      FOREACH_VALID({
        int bn = (int)((bpk[eidx >> 2] >> ((eidx & 3) * 8)) & 255u);
        bool pred = (bn == sb0);
        if (pred && sub0 >= 0) {
          int sb2 = (int)((bf2f(bits) - lo) * sc1);
          sb2 = sb2 < 0 ? 0 : (sb2 > 255 ? 255 : sb2);
          pred = (sb2 == sub0);
        }
        if (pred) {
          unsigned pos = atomicAdd(lcnt, 1u);
          if (pos < 64u) list[pos] = akey16(bits);
        }
      })
      int cc = c < 64 ? c : 64;
      if (R > cc) R = cc;
      unsigned key = (lane < cc) ? list[lane] : 0u;
      ull active = __ballot(lane < cc);
      unsigned ak = 0;
      if (largest) {
        #pragma unroll
        for (int bit = 15; bit >= 0; --bit) {
          ull ones = __ballot(((key >> bit) & 1u) != 0u) & active;
          int cnt1 = __popcll(ones);
          if (cnt1 >= R) { active = ones; ak |= 1u << bit; }
          else R -= cnt1;
          if (cnt1 < R + cnt1 && cnt1 < 64) active = (cnt1 >= R + cnt1) ? active : active; // no-op
          if (!(cnt1 >= R + 0) && false) {}
          if (cnt1 < 0) {}
          if (!((ak >> bit) & 1u)) active &= ~ones;
        }
      } else {
        #pragma unroll
        for (int bit = 15; bit >= 0; --bit) {
          ull ones = __ballot(((key >> bit) & 1u) != 0u) & active;
          ull zmask = active & ~ones;
          int cnt0 = __popcll(zmask);
          if (R <= cnt0) { active = zmask; }
          else { R -= cnt0; active = ones; ak |= 1u << bit; }
        }
      }
      return ak;
    };

    akT = gatherSel(true, sbT, RT, cT);
    akB = gatherSel(false, sbB, RB, cB);
  }

  const float tT = akey2f(akT);
  const float tB = akey2f(akB);

  // final pass: exact tie-aware sums vs exact bf16 thresholds
  float sT = 0.f, sB = 0.f;
  int cgt = 0, clt = 0;
  FOREACH_VALID({
    (void)eidx;
    unsigned ak = akey16(bits);
    float x = bf2f(bits);
    if (ak > akT) { sT += x; cgt++; }
    if (ak < akB) { sB += x; clt++; }
  })
  #pragma unroll
  for (int off = 1; off < 64; off <<= 1) {
    sT += __shfl_xor(sT, off);
    sB += __shfl_xor(sB, off);
    cgt += __shfl_xor(cgt, off);
    clt += __shfl_xor(clt, off);
  }

  if (lane == 0) {
    float top_sum = sT + tT * (float)(ksel - cgt);
    float bot_sum = sB + tB * (float)(lsel - clt);
    float alpha = log1pf(expf(alpha_raw[0]));
    float beta = log1pf(expf(beta_raw[0]));
    float total_mean = tsum / (float)n_pair;
    float top_mean = top_sum / (float)ksel;
    float bm = fmaxf(0.0f, -(bot_sum / (float)lsel));
    out[pair] = total_mean + alpha * top_mean - beta * bm;
  }
}
#undef FOREACH_VALID

// ========== last-resort fused fallback (no workspace) ==========
__device__ __forceinline__ void scanTopSum(const unsigned* hC, const float* hS,
                                           int lane, int R, int& selB, int& Rin,
                                           int& cnt, float& sumAbove, float& binSum) {
  uint4 c4 = ((const uint4*)hC)[lane];
  float4 s4 = ((const float4*)hS)[lane];
  unsigned lc = c4.x + c4.y + c4.z + c4.w;
  float ls = s4.x + s4.y + s4.z + s4.w;
  unsigned run = lc; float runv = ls;
  #pragma unroll
  for (int off = 1; off < 64; off <<= 1) {
    unsigned o = __shfl_down(run, off);
    float ov = __shfl_down(runv, off);
    if (lane + off < 64) { run += o; runv += ov; }
  }
  unsigned above = run - lc; float vabove = runv - ls;
  bool found = ((unsigned)R > above) && ((unsigned)R <= run);
  int sb = 0, ri = 0, cc = 0; float sa = 0.f, bs = 0.f;
  if (found) {
    unsigned a = above; float va = vabove;
    if ((unsigned)R <= a + c4.w) { sb = 3; ri = R - (int)a; cc = (int)c4.w; sa = va; bs = s4.w; }
    else { a += c4.w; va += s4.w;
    if ((unsigned)R <= a + c4.z) { sb = 2; ri = R - (int)a; cc = (int)c4.z; sa = va; bs = s4.z; }
    else { a += c4.z; va += s4.z;
    if ((unsigned)R <= a + c4.y) { sb = 1; ri = R - (int)a; cc = (int)c4.y; sa = va; bs = s4.y; }
    else { a += c4.y; va += s4.y; sb = 0; ri = R - (int)a; cc = (int)c4.x; sa = va; bs = s4.x; } } }
    sb += lane * 4;
  }
  ull fm = __ballot(found);
  int src = fm ? (int)__builtin_ctzll(fm) : 0;
  selB = __shfl(sb, src); Rin = __shfl(ri, src);
  cnt = __shfl(cc, src); sumAbove = __shfl(sa, src); binSum = __shfl(bs, src);
}

__device__ __forceinline__ void scanBotSum(const unsigned* hC, const float* hS,
                                           int lane, int R, int& selB, int& Rin,
                                           int& cnt, float& sumBelow, float& binSum) {
  uint4 c4 = ((const uint4*)hC)[lane];
  float4 s4 = ((const float4*)hS)[lane];
  unsigned lc = c4.x + c4.y + c4.z + c4.w;
  float ls = s4.x + s4.y + s4.z + s4.w;
  unsigned run = lc; float runv = ls;
  #pragma unroll
  for (int off = 1; off < 64; off <<= 1) {
    unsigned o = __shfl_up(run, off);
    float ov = __shfl_up(runv, off);
    if (lane >= off) { run += o; runv += ov; }
  }
  unsigned below = run - lc; float vbelow = runv - ls;
  bool found = ((unsigned)R > below) && ((unsigned)R <= run);
  int sb = 0, ri = 0, cc = 0; float sa = 0.f, bs = 0.f;
  if (found) {
    unsigned a = below; float va = vbelow;
    if ((unsigned)R <= a + c4.x) { sb = 0; ri = R - (int)a; cc = (int)c4.x; sa = va; bs = s4.x; }
    else { a += c4.x; va += s4.x;
    if ((unsigned)R <= a + c4.y) { sb = 1; ri = R - (int)a; cc = (int)c4.y; sa = va; bs = s4.y; }
    else { a += c4.y; va += s4.y;
    if ((unsigned)R <= a + c4.z) { sb = 2; ri = R - (int)a; cc = (int)c4.z; sa = va; bs = s4.z; }
    else { a += c4.z; va += s4.z; sb = 3; ri = R - (int)a; cc = (int)c4.w; sa = va; bs = s4.w; } } }
    sb += lane * 4;
  }
  ull fm = __ballot(found);
  int src = fm ? (int)__builtin_ctzll(fm) : 0;
  selB = __shfl(sb, src); Rin = __shfl(ri, src);
  cnt = __shfl(cc, src); sumBelow = __shfl(sa, src); binSum = __shfl(bs, src);
}

__global__ __launch_bounds__(TB, 3) void dpr_fused0(
    const float* __restrict__ q_emb, const float* __restrict__ p_emb,
    const void* __restrict__ qmr, const void* __restrict__ pmr,
    const float* __restrict__ alpha_raw, const float* __restrict__ beta_raw,
    float* __restrict__ out) {
  __shared__ __align__(16) char arena[32768];
  unsigned short* Al = (unsigned short*)arena;
  unsigned short* Bl = (unsigned short*)(arena + 16384);
  const int tid = threadIdx.x, lane = tid & 63, wid = tid >> 6;
  const int bid = blockIdx.x, blockB = bid >> 6, blockP = bid & 63;
  const int lr = lane & 15, lg = lane >> 4;
  const int db = wid >> 1, dp = wid & 1;

  bool m32 = true;
  {
    const unsigned* qm32 = (const unsigned*)qmr;
    #pragma unroll
    for (int i = 0; i < 8; ++i) m32 = m32 && (qm32[i] <= 1u);
  }
  int qrow = (blockB * 2 + db) * 64 + lane;
  int pcolg = (blockP * 2 + dp) * 64 + lane;
  bool qvb = m32 ? (((const int*)qmr)[qrow] != 0) : (((const unsigned char*)qmr)[qrow] != 0);
  bool pvb = m32 ? (((const int*)pmr)[pcolg] != 0) : (((const unsigned char*)pmr)[pcolg] != 0);
  ull qb = __ballot(qvb);
  ull pb = __ballot(pvb);
  const int n_pair = __popcll(qb) * __popcll(pb);

  f32x4 acc[4][4];
  #pragma unroll
  for (int m = 0; m < 4; ++m)
    #pragma unroll
    for (int n = 0; n < 4; ++n)
      acc[m][n] = f32x4{0.f, 0.f, 0.f, 0.f};

  const float* Abase = q_emb + (size_t)(blockB * 128) * 768;
  const float* Bbase = p_emb + (size_t)(blockP * 128) * 768;

  for (int kt = 0; kt < 12; ++kt) {
    const int k0 = kt * 64;
    #pragma unroll
    for (int it = 0; it < 4; ++it) {
      int gg = tid + 256 * it;
      int row = gg >> 3;
      int col = (gg & 7) * 8;
      int off = (row * 128 + col * 2) ^ ((row & 7) << 4);
      const float4* sA = (const float4*)(Abase + (size_t)row * 768 + k0 + col);
      float4 a0 = sA[0], a1 = sA[1];
      uint4 wv;
      wv.x = pack2bf(a0.x, a0.y); wv.y = pack2bf(a0.z, a0.w);
      wv.z = pack2bf(a1.x, a1.y); wv.w = pack2bf(a1.z, a1.w);
      *(uint4*)((char*)Al + off) = wv;
      const float4* sB = (const float4*)(Bbase + (size_t)row * 768 + k0 + col);
      float4 b0 = sB[0], b1 = sB[1];
      wv.x = pack2bf(b0.x, b0.y); wv.y = pack2bf(b0.z, b0.w);
      wv.z = pack2bf(b1.x, b1.y); wv.w = pack2bf(b1.z, b1.w);
      *(uint4*)((char*)Bl + off) = wv;
    }
    __syncthreads();
    #pragma unroll
    for (int ks = 0; ks < 2; ++ks) {
      bf16x8 af[4], bfr[4];
      #pragma unroll
      for (int m = 0; m < 4; ++m) {
        int row = db * 64 + m * 16 + lr;
        int off = (row * 128 + ks * 64 + lg * 16) ^ ((row & 7) << 4);
        af[m] = *(const bf16x8*)((const char*)Al + off);
      }
      #pragma unroll
      for (int n = 0; n < 4; ++n) {
        int row = dp * 64 + n * 16 + lr;
        int off = (row * 128 + ks * 64 + lg * 16) ^ ((row & 7) << 4);
        bfr[n] = *(const bf16x8*)((const char*)Bl + off);
      }
      #pragma unroll
      for (int m = 0; m < 4; ++m)
        #pragma unroll
        for (int n = 0; n < 4; ++n)
          acc[m][n] = __builtin_amdgcn_mfma_f32_16x16x32_bf16(af[m], bfr[n], acc[m][n], 0, 0, 0);
    }
    __syncthreads();
  }

  const int outIdx = (blockB * 2 + db) * 128 + (blockP * 2 + dp);
  if (n_pair == 0) {
    if (lane == 0) out[outIdx] = -1e9f;
    return;
  }

  unsigned vlo = 0, vhi = 0;
  {
    unsigned qn[4], pc[4];
    #pragma unroll
    for (int m = 0; m < 4; ++m) qn[m] = (unsigned)((qb >> (m * 16 + lg * 4)) & 0xFull);
    #pragma unroll
    for (int n = 0; n < 4; ++n) pc[n] = ((pb >> (n * 16 + lr)) & 1ull) ? 0xFu : 0u;
    #pragma unroll
    for (int m = 0; m < 2; ++m)
      #pragma unroll
      for (int n = 0; n < 4; ++n) vlo |= (qn[m] & pc[n]) << ((m * 4 + n) * 4);
    #pragma unroll
    for (int m = 2; m < 4; ++m)
      #pragma unroll
      for (int n = 0; n < 4; ++n) vhi |= (qn[m] & pc[n]) << (((m - 2) * 4 + n) * 4);
  }
  #define VBIT(idx) ((idx) < 32 ? ((vlo >> (idx)) & 1u) : ((vhi >> ((idx) - 32)) & 1u))

  float tsum = 0.f, mn = INFINITY, mx = -INFINITY;
  #pragma unroll
  for (int m = 0; m < 4; ++m)
    #pragma unroll
    for (int n = 0; n < 4; ++n)
      #pragma unroll
      for (int j = 0; j < 4; ++j) {
        const int idx = (m * 4 + n) * 4 + j;
        float x = acc[m][n][j];
        if (VBIT(idx)) { tsum += x; mn = fminf(mn, x); mx = fmaxf(mx, x); }
      }
  #pragma unroll
  for (int off = 1; off < 64; off <<= 1) {
    tsum += __shfl_xor(tsum, off);
    mn = fminf(mn, __shfl_xor(mn, off));
    mx = fmaxf(mx, __shfl_xor(mx, off));
  }

  int ksel = 4 * n_pair / 10; if (ksel < 1) ksel = 1;
  int lsel = 2 * n_pair / 10; if (lsel < 1) lsel = 1;

  unsigned* hC = (unsigned*)(arena + wid * 2048);
  float* hS = (float*)(arena + wid * 2048 + 1024);

  float topS, botS;
  if (!(mx > mn)) {
    topS = (float)ksel * mn;
    botS = (float)lsel * mn;
  } else {
    const float w0 = (mx - mn) * (1.0f / 256.0f);
    const float sc0 = 1.0f / w0;
    ((uint4*)hC)[lane] = uint4{0u, 0u, 0u, 0u};
    ((float4*)hS)[lane] = float4{0.f, 0.f, 0.f, 0.f};
    #pragma unroll
    for (int m = 0; m < 4; ++m)
      #pragma unroll
      for (int n = 0; n < 4; ++n)
        #pragma unroll
        for (int j = 0; j < 4; ++j) {
          const int idx = (m * 4 + n) * 4 + j;
          if (VBIT(idx)) {
            float x = acc[m][n][j];
            int bn = (int)((x - mn) * sc0);
            bn = bn < 0 ? 0 : (bn > 255 ? 255 : bn);
            atomicAdd(&hC[bn], 1u);
            atomicAdd(&hS[bn], x);
          }
        }
    int sbT, RT, cT; float sumA, sBinT;
    int sbB, RB, cB; float sumBlw, sBinB;
    scanTopSum(hC, hS, lane, ksel, sbT, RT, cT, sumA, sBinT);
    scanBotSum(hC, hS, lane, lsel, sbB, RB, cB, sumBlw, sBinB);

    auto refine = [&](bool largest, int sb0, int R0, int c0, float binSum0) -> float {
      if (R0 >= c0) return binSum0;
      float lo1 = mn + w0 * (float)sb0;
      if (!(w0 > 0.f)) return binSum0 * ((float)R0 / (float)c0);
      ((uint4*)hC)[lane] = uint4{0u, 0u, 0u, 0u};
      ((float4*)hS)[lane] = float4{0.f, 0.f, 0.f, 0.f};
      const float sc1 = 256.0f / w0;
      #pragma unroll
      for (int m = 0; m < 4; ++m)
        #pragma unroll
        for (int n = 0; n < 4; ++n)
          #pragma unroll
          for (int j = 0; j < 4; ++j) {
            const int idx = (m * 4 + n) * 4 + j;
            if (VBIT(idx)) {
              float x = acc[m][n][j];
              int b0e = (int)((x - mn) * sc0);
              b0e = b0e < 0 ? 0 : (b0e > 255 ? 255 : b0e);
              if (b0e == sb0) {
                int b1 = (int)((x - lo1) * sc1);
                b1 = b1 < 0 ? 0 : (b1 > 255 ? 255 : b1);
                atomicAdd(&hC[b1], 1u);
                atomicAdd(&hS[b1], x);
              }
            }
          }
      int sb2, R2, c2; float above2, bs2;
      if (largest) scanTopSum(hC, hS, lane, R0, sb2, R2, c2, above2, bs2);
      else         scanBotSum(hC, hS, lane, R0, sb2, R2, c2, above2, bs2);
      if (c2 <= 0) return binSum0 * ((float)R0 / (float)c0);
      return above2 + bs2 * ((float)R2 / (float)c2);
    };

    topS = sumA + refine(true, sbT, RT, cT, sBinT);
    botS = sumBlw + refine(false, sbB, RB, cB, sBinB);
  }
  #undef VBIT

  if (lane == 0) {
    float alpha = log1pf(expf(alpha_raw[0]));
    float beta = log1pf(expf(beta_raw[0]));
    float total_mean = tsum / (float)n_pair;
    float top_mean = topS / (float)ksel;
    float bm = fmaxf(0.0f, -(botS / (float)lsel));
    out[outIdx] = total_mean + alpha * top_mean - beta * bm;
  }
}

extern "C" void kernel_launch(void* const* d_in, const int* in_sizes, int n_in,
                              void* d_out, int out_size, void* d_ws, size_t ws_size,
                              hipStream_t stream) {
  (void)in_sizes; (void)n_in; (void)out_size;
  const float* q_emb = (const float*)d_in[0];
  const float* p_emb = (const float*)d_in[1];
  const void* q_mask = d_in[2];
  const void* p_mask = d_in[3];
  const float* alpha_raw = (const float*)d_in[4];
  const float* beta_raw = (const float*)d_in[5];
  float* out = (float*)d_out;

  if (ws_size >= NEED_T + NEED_S) {
    unsigned char* qt = (unsigned char*)d_ws;
    unsigned char* pt = qt + (size_t)NA_G * 16;
    unsigned short* Sb = (unsigned short*)((unsigned char*)d_ws + NEED_T);
    hipLaunchKernelGGL(convert_pack, dim3((NA_G + NB_G) / 256), dim3(256), 0, stream,
                       q_emb, p_emb, qt, pt);
    hipLaunchKernelGGL((dpr_gemm<1>), dim3(2048), dim3(TB), 0, stream,
                       q_emb, p_emb, qt, pt, Sb);
    hipLaunchKernelGGL(dpr_select, dim3(2048), dim3(TB), 0, stream,
                       Sb, q_mask, p_mask, alpha_raw, beta_raw, out);
  } else if (ws_size >= NEED_S) {
    unsigned short* Sb = (unsigned short*)d_ws;
    hipLaunchKernelGGL((dpr_gemm<0>), dim3(2048), dim3(TB), 0, stream,
                       q_emb, p_emb,
                       (const unsigned char*)nullptr, (const unsigned char*)nullptr, Sb);
    hipLaunchKernelGGL(dpr_select, dim3(2048), dim3(TB), 0, stream,
                       Sb, q_mask, p_mask, alpha_raw, beta_raw, out);
  } else {
    hipLaunchKernelGGL(dpr_fused0, dim3(2048), dim3(TB), 0, stream,
                       q_emb, p_emb, q_mask, p_mask, alpha_raw, beta_raw, out);
  }
}